// Round 1
// baseline (218.481 us; speedup 1.0000x reference)
//
#include <hip/hip_runtime.h>

// ALiBi bias subtraction: out[b,h,i,j] = scores[b,h,i,j] - slope(h)*((i+off)-(j+off))
//                       = scores[b,h,i,j] - slope(h)*(i-j)       (offset cancels)
// B=2, H=16, S=2048 (all powers of two -> shift/mask index decomposition).
// Pure streaming op: float4 vectorized, grid-stride, 2048 blocks x 256 threads.

__global__ __launch_bounds__(256) void alibi_kernel(const float4* __restrict__ in,
                                                    float4* __restrict__ out,
                                                    unsigned int n4) {
    const unsigned int stride = gridDim.x * blockDim.x;
    for (unsigned int idx4 = blockIdx.x * blockDim.x + threadIdx.x; idx4 < n4; idx4 += stride) {
        const unsigned int e = idx4 << 2;              // element index of lane's .x
        const int j = (int)(e & 2047u);                // S = 2048
        const int i = (int)((e >> 11) & 2047u);
        const int h = (int)((e >> 22) & 15u);          // H = 16
        // slope = 2^(-8*(h+1)/16) = exp2(-0.5*(h+1))
        const float slope = exp2f(-0.5f * (float)(h + 1));
        const int d = i - j;                            // exact in fp32 range
        float4 s = in[idx4];
        float4 o;
        o.x = s.x - slope * (float)(d);
        o.y = s.y - slope * (float)(d - 1);
        o.z = s.z - slope * (float)(d - 2);
        o.w = s.w - slope * (float)(d - 3);
        out[idx4] = o;
    }
}

extern "C" void kernel_launch(void* const* d_in, const int* in_sizes, int n_in,
                              void* d_out, int out_size, void* d_ws, size_t ws_size,
                              hipStream_t stream) {
    const float4* in = (const float4*)d_in[0];
    float4* out = (float4*)d_out;
    // out_size = B*H*S*S = 134217728 elements; n4 = /4 float4s
    const unsigned int n4 = (unsigned int)(out_size / 4);
    const int block = 256;
    const int grid = 2048;  // 8 blocks/CU * 256 CUs -> full occupancy, grid-stride covers rest
    alibi_kernel<<<grid, block, 0, stream>>>(in, out, n4);
}